// Round 12
// baseline (724.936 us; speedup 1.0000x reference)
//
#include <hip/hip_runtime.h>
#include <hip/hip_bf16.h>

// ---------------------------------------------------------------------------
// GCN surface: 4x GCNConv(tanh) + global max/mean pool + 3-layer MLP
// Round 12 (bit-exact consolidation; msgpass structure frozen at round-8 form):
//   - col[] as ushort (N<65536): halves col stream in msgpass x4 + scatter
//     payload; col loads nontemporal (don't evict h rows from L2)
//   - GEMM BK 32->64: halves __syncthreads count (short K-loop => barrier
//     drain matters); same MFMA order -> bit-identical accumulation
//   - cast_x + weight transposes fused into one prep launch
//   - msgpass untouched (fabric-BW equilibrium: 5 attacks confirmed 355 MB
//     @3.4 TB/s is the operating point; traffic cuts always cost more)
// ---------------------------------------------------------------------------

#define NNODES 50000
#define DDIM 256
#define SCAN_B 256
#define SCAN_G ((NNODES + SCAN_B - 1) / SCAN_B)   // 196

typedef __attribute__((ext_vector_type(8))) short short8;
typedef __attribute__((ext_vector_type(4))) float float4_;
typedef __attribute__((ext_vector_type(2))) float float2_;

__device__ __forceinline__ float fast_tanh(float x) {
    float e = __expf(2.0f * x);
    return 1.0f - 2.0f / (e + 1.0f);
}

__device__ __forceinline__ float bf2f(unsigned short u) {
    return __uint_as_float(((unsigned)u) << 16);
}
__device__ __forceinline__ unsigned short f2bf(float f) {
    unsigned u = __float_as_uint(f);
    u = u + 0x7fffu + ((u >> 16) & 1u);   // round-to-nearest-even
    return (unsigned short)(u >> 16);
}

__device__ __forceinline__ unsigned f2key(float f) {
    unsigned b = __float_as_uint(f);
    return (b & 0x80000000u) ? ~b : (b | 0x80000000u);
}
__device__ __forceinline__ float key2f(unsigned k) {
    unsigned b = (k & 0x80000000u) ? (k & 0x7fffffffu) : ~k;
    return __uint_as_float(b);
}

// ---------------- CSR build ----------------
__global__ void hist_kernel(const int* __restrict__ ei, int* __restrict__ deg,
                            int* __restrict__ rank, int E) {
    int e = blockIdx.x * blockDim.x + threadIdx.x;
    if (e < E) rank[e] = atomicAdd(&deg[ei[E + e]], 1);
}

__global__ void scan1_kernel(const int* __restrict__ deg, int* __restrict__ bsum, int N) {
    __shared__ int s[SCAN_B];
    int t = threadIdx.x;
    int idx = blockIdx.x * SCAN_B + t;
    s[t] = (idx < N) ? deg[idx] : 0;
    __syncthreads();
    for (int off = SCAN_B / 2; off > 0; off >>= 1) {
        if (t < off) s[t] += s[t + off];
        __syncthreads();
    }
    if (t == 0) bsum[blockIdx.x] = s[0];
}

__global__ void scan2_kernel(const int* __restrict__ deg, const int* __restrict__ bsum,
                             int* __restrict__ rowptr, float* __restrict__ dis, int N) {
    __shared__ int s[SCAN_B];
    __shared__ int bs[SCAN_B];
    int t = threadIdx.x;
    int bid = blockIdx.x;
    int idx = bid * SCAN_B + t;
    int d = (idx < N) ? deg[idx] : 0;
    s[t] = d;
    bs[t] = (t < bid) ? bsum[t] : 0;      // SCAN_G (196) <= SCAN_B (256)
    __syncthreads();
    for (int off = 1; off < SCAN_B; off <<= 1) {
        int v = (t >= off) ? s[t - off] : 0;
        __syncthreads();
        s[t] += v;
        __syncthreads();
    }
    for (int off = SCAN_B / 2; off > 0; off >>= 1) {
        if (t < off) bs[t] += bs[t + off];
        __syncthreads();
    }
    if (idx < N) {
        rowptr[idx] = bs[0] + s[t] - d;   // exclusive
        dis[idx] = rsqrtf(1.0f + (float)d);
    }
}

__global__ void scatter_kernel(const int* __restrict__ ei, const int* __restrict__ rowptr,
                               const int* __restrict__ rank,
                               unsigned short* __restrict__ col, int E) {
    int e = blockIdx.x * blockDim.x + threadIdx.x;
    if (e < E) {
        int d = ei[E + e];
        col[rowptr[d] + rank[e]] = (unsigned short)ei[e];
    }
}

// ---------------- prep: cast x (pre-scaled by dis) + 4 weight transposes ----
#define CAST_BLOCKS ((NNODES * 128) / 256)     // 25000
__global__ void prep_kernel(const float* __restrict__ x, const float* __restrict__ dis,
                            unsigned short* __restrict__ xh,
                            const float* __restrict__ W0, const float* __restrict__ W1,
                            const float* __restrict__ W2, const float* __restrict__ W3,
                            unsigned short* __restrict__ wt0, unsigned short* __restrict__ wt1,
                            unsigned short* __restrict__ wt2, unsigned short* __restrict__ wt3) {
    int b = blockIdx.x;
    int t = threadIdx.x;
    if (b < CAST_BLOCKS) {
        int i = b * 256 + t;
        xh[i] = f2bf(x[i] * dis[i >> 7]);   // 128 feats per row
        return;
    }
    b -= CAST_BLOCKS;
    const float* W; unsigned short* Wt; int K; int k;
    if (b < 128)      { W = W0; Wt = wt0; K = 128; k = b; }
    else if (b < 384) { W = W1; Wt = wt1; K = 256; k = b - 128; }
    else if (b < 640) { W = W2; Wt = wt2; K = 256; k = b - 384; }
    else              { W = W3; Wt = wt3; K = 256; k = b - 640; }
    Wt[t * K + k] = f2bf(W[k * 256 + t]);
}

// ---------------- message passing (round-8 form, frozen) ----------------
// in rows pre-scaled by dis[src]; out[n] = dis[n]*(sum in[src] + in[n]).
// Lane covers 8 feats (16B); P = 512/D edges per wave-issue; acc = 4x float2.
__device__ __forceinline__ void paddu(float2_* acc, uint4 u) {
    float2_ v0 = {__uint_as_float(u.x << 16), __uint_as_float(u.x & 0xffff0000u)};
    float2_ v1 = {__uint_as_float(u.y << 16), __uint_as_float(u.y & 0xffff0000u)};
    float2_ v2 = {__uint_as_float(u.z << 16), __uint_as_float(u.z & 0xffff0000u)};
    float2_ v3 = {__uint_as_float(u.w << 16), __uint_as_float(u.w & 0xffff0000u)};
    acc[0] += v0; acc[1] += v1; acc[2] += v2; acc[3] += v3;
}
__device__ __forceinline__ void paddw(float2_* acc, uint4 u, float w) {
    float2_ w2 = {w, w};
    float2_ v0 = {__uint_as_float(u.x << 16), __uint_as_float(u.x & 0xffff0000u)};
    float2_ v1 = {__uint_as_float(u.y << 16), __uint_as_float(u.y & 0xffff0000u)};
    float2_ v2 = {__uint_as_float(u.z << 16), __uint_as_float(u.z & 0xffff0000u)};
    float2_ v3 = {__uint_as_float(u.w << 16), __uint_as_float(u.w & 0xffff0000u)};
    acc[0] += v0 * w2; acc[1] += v1 * w2; acc[2] += v2 * w2; acc[3] += v3 * w2;
}

template <int D, bool FINALIZE>
__global__ void msgpass_bf16(const unsigned short* __restrict__ in,
                             unsigned short* __restrict__ out,
                             const int* __restrict__ rowptr, const int* __restrict__ deg,
                             const unsigned short* __restrict__ col,
                             const float* __restrict__ dis, const float* __restrict__ bias) {
    constexpr int L = D / 8;
    constexpr int P = 64 / L;
    int lane = threadIdx.x & 63;
    int wav  = threadIdx.x >> 6;
    int n = blockIdx.x * 8 + wav;   // block = 512 threads = 8 waves
    if (n >= NNODES) return;
    int part = lane / L;
    int sl   = lane % L;
    int start = rowptr[n];
    int cnt   = deg[n];
    float dn = dis[n];
    float2_ acc[4];
#pragma unroll
    for (int j = 0; j < 4; ++j) { float2_ z = {0.0f, 0.0f}; acc[j] = z; }

    int e = 0;
    for (; e + 4 * P <= cnt; e += 4 * P) {
        int c0 = __builtin_nontemporal_load(&col[start + e + part]);
        int c1 = __builtin_nontemporal_load(&col[start + e + P + part]);
        int c2 = __builtin_nontemporal_load(&col[start + e + 2 * P + part]);
        int c3 = __builtin_nontemporal_load(&col[start + e + 3 * P + part]);
        uint4 u0 = *((const uint4*)(in + (size_t)c0 * D) + sl);
        uint4 u1 = *((const uint4*)(in + (size_t)c1 * D) + sl);
        uint4 u2 = *((const uint4*)(in + (size_t)c2 * D) + sl);
        uint4 u3 = *((const uint4*)(in + (size_t)c3 * D) + sl);
        paddu(acc, u0);
        paddu(acc, u1);
        paddu(acc, u2);
        paddu(acc, u3);
    }
    for (; e + P <= cnt; e += P) {
        int c = __builtin_nontemporal_load(&col[start + e + part]);
        uint4 u = *((const uint4*)(in + (size_t)c * D) + sl);
        paddu(acc, u);
    }
    int r = cnt - e;
    if (r > 0) {
        int c = (part < r) ? (int)__builtin_nontemporal_load(&col[start + e + part]) : n;
        float w = (part < r) ? 1.0f : 0.0f;
        uint4 u = *((const uint4*)(in + (size_t)c * D) + sl);
        paddw(acc, u, w);
    }
    {   // self term: + in[n] (part 0 only)
        float w = (part == 0) ? 1.0f : 0.0f;
        uint4 u = *((const uint4*)(in + (size_t)n * D) + sl);
        paddw(acc, u, w);
    }
    // reduce across parts (butterfly)
#pragma unroll
    for (int j = 0; j < 4; ++j) {
#pragma unroll
        for (int h = 0; h < 2; ++h) {
            if (P == 4) acc[j][h] += __shfl(acc[j][h], lane ^ 16);
            acc[j][h] += __shfl(acc[j][h], lane ^ 32);
        }
    }
    if (part == 0) {
        float a[8] = {acc[0][0], acc[0][1], acc[1][0], acc[1][1],
                      acc[2][0], acc[2][1], acc[3][0], acc[3][1]};
        if (FINALIZE) {
#pragma unroll
            for (int j = 0; j < 8; ++j)
                a[j] = fast_tanh(fmaf(a[j], dn, bias[sl * 8 + j]));
        } else {
#pragma unroll
            for (int j = 0; j < 8; ++j)
                a[j] *= dn;
        }
        uint4 o;
        o.x = (unsigned)f2bf(a[0]) | ((unsigned)f2bf(a[1]) << 16);
        o.y = (unsigned)f2bf(a[2]) | ((unsigned)f2bf(a[3]) << 16);
        o.z = (unsigned)f2bf(a[4]) | ((unsigned)f2bf(a[5]) << 16);
        o.w = (unsigned)f2bf(a[6]) | ((unsigned)f2bf(a[7]) << 16);
        *((uint4*)(out + (size_t)n * D) + sl) = o;
    }
}

// ---------------- MFMA GEMM: C[N,256] = A[N,K] * W[K,256], BK=64 ----------
// TANH: C = tanh(AW + bias); else C = dis[row]*(AW) (pre-scaled for msgpass).
// Same MFMA accumulation order as BK=32 version -> bit-identical results.
template <int K, bool TANH>
__launch_bounds__(256, 2)
__global__ void gemm_mfma(const short* __restrict__ A, const short* __restrict__ Bt,
                          const float* __restrict__ bias, const float* __restrict__ dis,
                          unsigned short* __restrict__ C, int N) {
    constexpr int PK = 72;   // 64 + 8 pad (16B-aligned segments)
    __shared__ __align__(16) short As[128 * PK];
    __shared__ __align__(16) short Bs[128 * PK];
    int t = threadIdx.x;
    int lane = t & 63;
    int w    = t >> 6;
    int wr = w & 1;
    int wc = w >> 1;
    int m0 = blockIdx.x * 128;
    int n0 = blockIdx.y * 128;

    int srow = t >> 2;           // 0..63
    int koff = (t & 3) * 8;      // 0,8,16,24
    int arow0 = m0 + srow;      if (arow0 > N - 1) arow0 = N - 1;
    int arow1 = m0 + 64 + srow; if (arow1 > N - 1) arow1 = N - 1;
    const short8* ap0 = (const short8*)(A + (size_t)arow0 * K + koff);
    const short8* ap1 = (const short8*)(A + (size_t)arow1 * K + koff);
    const short8* bp0 = (const short8*)(Bt + (size_t)(n0 + srow) * K + koff);
    const short8* bp1 = (const short8*)(Bt + (size_t)(n0 + 64 + srow) * K + koff);

    float4_ acc[4][4];
#pragma unroll
    for (int i = 0; i < 4; ++i)
#pragma unroll
        for (int j = 0; j < 4; ++j) {
            float4_ z = {0.0f, 0.0f, 0.0f, 0.0f};
            acc[i][j] = z;
        }

    constexpr int NKB = K / 64;       // 4 for K=256, 2 for K=128
    int g = lane >> 4;
    int r = lane & 15;

    // prologue: chunk 0 (two 32-wide sub-chunks per matrix half)
    short8 a00 = ap0[0], a01 = ap0[4];
    short8 a10 = ap1[0], a11 = ap1[4];
    short8 b00 = bp0[0], b01 = bp0[4];
    short8 b10 = bp1[0], b11 = bp1[4];

    for (int kb = 0; kb < NKB; ++kb) {
        __syncthreads();
        *(short8*)&As[srow * PK + koff]             = a00;
        *(short8*)&As[srow * PK + koff + 32]        = a01;
        *(short8*)&As[(64 + srow) * PK + koff]      = a10;
        *(short8*)&As[(64 + srow) * PK + koff + 32] = a11;
        *(short8*)&Bs[srow * PK + koff]             = b00;
        *(short8*)&Bs[srow * PK + koff + 32]        = b01;
        *(short8*)&Bs[(64 + srow) * PK + koff]      = b10;
        *(short8*)&Bs[(64 + srow) * PK + koff + 32] = b11;
        __syncthreads();
        if (kb + 1 < NKB) {
            int o = (kb + 1) * 8;
            a00 = ap0[o]; a01 = ap0[o + 4];
            a10 = ap1[o]; a11 = ap1[o + 4];
            b00 = bp0[o]; b01 = bp0[o + 4];
            b10 = bp1[o]; b11 = bp1[o + 4];
        }
#pragma unroll
        for (int s = 0; s < 2; ++s) {
            short8 af[4], bfr[4];
#pragma unroll
            for (int i = 0; i < 4; ++i)
                af[i] = *(const short8*)&As[(wr * 64 + i * 16 + r) * PK + s * 32 + g * 8];
#pragma unroll
            for (int j = 0; j < 4; ++j)
                bfr[j] = *(const short8*)&Bs[(wc * 64 + j * 16 + r) * PK + s * 32 + g * 8];
#pragma unroll
            for (int i = 0; i < 4; ++i)
#pragma unroll
                for (int j = 0; j < 4; ++j)
                    acc[i][j] = __builtin_amdgcn_mfma_f32_16x16x32_bf16(af[i], bfr[j],
                                                                        acc[i][j], 0, 0, 0);
        }
    }

#pragma unroll
    for (int i = 0; i < 4; ++i) {
        int rowb = m0 + wr * 64 + i * 16 + g * 4;
#pragma unroll
        for (int rr = 0; rr < 4; ++rr) {
            int row = rowb + rr;
            if (row < N) {
                float dsc = TANH ? 0.0f : dis[row];
#pragma unroll
                for (int j = 0; j < 4; ++j) {
                    int cb = n0 + wc * 64 + j * 16 + r;
                    float v = acc[i][j][rr];
                    if (TANH) v = fast_tanh(v + bias[cb]);
                    else      v = v * dsc;
                    C[(size_t)row * 256 + cb] = f2bf(v);
                }
            }
        }
    }
}

// ---------------- pooling (sorted batch index, run-flush), bf16 input -------
#define POOL_CHUNK 64
__global__ void pool_kernel(const unsigned short* __restrict__ act,
                            const int* __restrict__ batch,
                            float* __restrict__ gsum, unsigned* __restrict__ gmaxk,
                            int* __restrict__ gcnt, int N) {
    int t  = threadIdx.x;   // 256 = DDIM
    int n0 = blockIdx.x * POOL_CHUNK;
    if (n0 >= N) return;
    int n1 = n0 + POOL_CHUNK;
    if (n1 > N) n1 = N;
    int   cur = batch[n0];
    float sum = 0.0f, mx = -2.0f;
    int   run = 0;
    for (int n = n0; n < n1; ++n) {
        int g = batch[n];
        float v = bf2f(act[(size_t)n * DDIM + t]);
        if (g != cur) {
            atomicAdd(&gsum[cur * DDIM + t], sum);
            atomicMax(&gmaxk[cur * DDIM + t], f2key(mx));
            if (t == 0) atomicAdd(&gcnt[cur], run);
            cur = g; sum = 0.0f; mx = -2.0f; run = 0;
        }
        sum += v;
        mx = fmaxf(mx, v);
        run++;
    }
    atomicAdd(&gsum[cur * DDIM + t], sum);
    atomicMax(&gmaxk[cur * DDIM + t], f2key(mx));
    if (t == 0) atomicAdd(&gcnt[cur], run);
}

// ---------------- fused MLP (one WG per graph), fp32 ----------------
__global__ void mlp_kernel(const float* __restrict__ gsum, const unsigned* __restrict__ gmaxk,
                           const int* __restrict__ gcnt,
                           const float* __restrict__ fc1_w, const float* __restrict__ fc1_b,
                           const float* __restrict__ fc2_w, const float* __restrict__ fc2_b,
                           const float* __restrict__ out_w, const float* __restrict__ out_b,
                           float* __restrict__ out) {
    int g = blockIdx.x;
    int t = threadIdx.x;   // 256
    __shared__ float gv[512];
    __shared__ float t1[512];
    __shared__ float t2[256];
    float cnt = fmaxf((float)gcnt[g], 1.0f);
    gv[t]       = key2f(gmaxk[g * DDIM + t]);
    gv[256 + t] = gsum[g * DDIM + t] / cnt;
    __syncthreads();
    float a0 = fc1_b[t], a1 = fc1_b[t + 256];
    for (int k = 0; k < 512; ++k) {
        float gk = gv[k];
        a0 = fmaf(gk, fc1_w[k * 512 + t], a0);
        a1 = fmaf(gk, fc1_w[k * 512 + t + 256], a1);
    }
    t1[t]       = fmaxf(a0, 0.0f);
    t1[t + 256] = fmaxf(a1, 0.0f);
    __syncthreads();
    float b0 = fc2_b[t];
    for (int k = 0; k < 512; ++k)
        b0 = fmaf(t1[k], fc2_w[k * 256 + t], b0);
    t2[t] = fmaxf(b0, 0.0f);
    __syncthreads();
    if (t < 10) {
        float o = out_b[t];
        for (int k = 0; k < 256; ++k)
            o = fmaf(t2[k], out_w[k * 10 + t], o);
        out[g * 10 + t] = o;
    }
}

// ---------------------------------------------------------------------------
extern "C" void kernel_launch(void* const* d_in, const int* in_sizes, int n_in,
                              void* d_out, int out_size, void* d_ws, size_t ws_size,
                              hipStream_t stream) {
    const float* x      = (const float*)d_in[0];
    const int*   ei     = (const int*)d_in[1];
    const int*   batch  = (const int*)d_in[2];
    const float* W0     = (const float*)d_in[3];
    const float* b0     = (const float*)d_in[4];
    const float* W1     = (const float*)d_in[5];
    const float* b1     = (const float*)d_in[6];
    const float* W2     = (const float*)d_in[7];
    const float* b2     = (const float*)d_in[8];
    const float* W3     = (const float*)d_in[9];
    const float* b3     = (const float*)d_in[10];
    const float* fc1_w  = (const float*)d_in[11];
    const float* fc1_b  = (const float*)d_in[12];
    const float* fc2_w  = (const float*)d_in[13];
    const float* fc2_b  = (const float*)d_in[14];
    const float* out_w  = (const float*)d_in[15];
    const float* out_b  = (const float*)d_in[16];
    float* out = (float*)d_out;

    const int N = in_sizes[2];          // 50000
    const int E = in_sizes[1] / 2;      // 1600000

    // workspace layout (bytes)
    char* ws = (char*)d_ws;
    const size_t off_deg    = 0;          // 200000
    const size_t off_gsum   = 200192;     // 65536
    const size_t off_gmaxk  = 265728;     // 65536
    const size_t off_gcnt   = 331264;     // 512
    const size_t ZERO_BYTES = 331776;
    const size_t off_dis    = 331776;     // 200000
    const size_t off_rowptr = 531968;     // 200000
    const size_t off_bsum   = 732160;     // 1024
    const size_t off_col    = 932352;     // E*2 = 3200000 (ushort)
    const size_t off_xh     = 7332352;    // 12800000
    const size_t off_wt0    = 20132352;   // 65536
    const size_t off_wt1    = 20197888;   // 131072
    const size_t off_wt2    = 20328960;   // 131072
    const size_t off_wt3    = 20460032;   // 131072
    const size_t off_bufA   = 20591104;   // 25600000
    const size_t off_bufB   = 46191104;   // 25600000

    int*            deg    = (int*)(ws + off_deg);
    float*          gsum   = (float*)(ws + off_gsum);
    unsigned*       gmaxk  = (unsigned*)(ws + off_gmaxk);
    int*            gcnt   = (int*)(ws + off_gcnt);
    float*          dis    = (float*)(ws + off_dis);
    int*            rowptr = (int*)(ws + off_rowptr);
    int*            bsum   = (int*)(ws + off_bsum);
    unsigned short* col    = (unsigned short*)(ws + off_col);
    unsigned short* xh     = (unsigned short*)(ws + off_xh);
    short*          wt0    = (short*)(ws + off_wt0);
    short*          wt1    = (short*)(ws + off_wt1);
    short*          wt2    = (short*)(ws + off_wt2);
    short*          wt3    = (short*)(ws + off_wt3);
    unsigned short* bufA   = (unsigned short*)(ws + off_bufA);
    unsigned short* bufB   = (unsigned short*)(ws + off_bufB);
    int*            rank   = (int*)(ws + off_bufA);   // overlay: dead before 1st GEMM

    hipMemsetAsync(ws, 0, ZERO_BYTES, stream);

    // CSR build
    hist_kernel<<<(E + 255) / 256, 256, 0, stream>>>(ei, deg, rank, E);
    scan1_kernel<<<SCAN_G, SCAN_B, 0, stream>>>(deg, bsum, N);
    scan2_kernel<<<SCAN_G, SCAN_B, 0, stream>>>(deg, bsum, rowptr, dis, N);
    scatter_kernel<<<(E + 255) / 256, 256, 0, stream>>>(ei, rowptr, rank, col, E);

    // prep: x cast (pre-scaled by dis) + all 4 weight transposes, one launch
    prep_kernel<<<CAST_BLOCKS + 896, 256, 0, stream>>>(
        x, dis, xh, W0, W1, W2, W3,
        (unsigned short*)wt0, (unsigned short*)wt1,
        (unsigned short*)wt2, (unsigned short*)wt3);

    // layer 0: agg0 = dis*(sum x'_src + x'_n) = A_hat x, then tanh(agg0 W0 + b0)
    msgpass_bf16<128, false><<<(N + 7) / 8, 512, 0, stream>>>(
        xh, bufB, rowptr, deg, col, dis, nullptr);
    gemm_mfma<128, true><<<dim3((N + 127) / 128, 2), 256, 0, stream>>>(
        (const short*)bufB, wt0, b0, dis, bufA, N);

    // layers 1..3: hW' = dis*(h W) (GEMM epilogue); h = tanh(dis*(sum hW'_src
    // + hW'_n) + b) == tanh(A_hat (h W) + b)
    const short* wts[3] = {wt1, wt2, wt3};
    const float* bs_[3] = {b1, b2, b3};
    for (int l = 0; l < 3; ++l) {
        gemm_mfma<256, false><<<dim3((N + 127) / 128, 2), 256, 0, stream>>>(
            (const short*)bufA, wts[l], nullptr, dis, bufB, N);
        msgpass_bf16<256, true><<<(N + 7) / 8, 512, 0, stream>>>(
            bufB, bufA, rowptr, deg, col, dis, bs_[l]);
    }

    // pooling + MLP (fp32)
    pool_kernel<<<(N + POOL_CHUNK - 1) / POOL_CHUNK, 256, 0, stream>>>(
        bufA, batch, gsum, gmaxk, gcnt, N);
    mlp_kernel<<<64, 256, 0, stream>>>(gsum, gmaxk, gcnt, fc1_w, fc1_b, fc2_w, fc2_b,
                                       out_w, out_b, out);
}

// Round 13
// 713.135 us; speedup vs baseline: 1.0165x; 1.0165x over previous
//
#include <hip/hip_runtime.h>
#include <hip/hip_bf16.h>

// ---------------------------------------------------------------------------
// GCN surface: 4x GCNConv(tanh) + global max/mean pool + 3-layer MLP
// Round 13 (surgical revert):
//   - col loads back to normal cached loads (round-12 nontemporal hint
//     REGRESSED: FETCH 355->362 MB, msgpass 105->107.5 us — col has high
//     short-range reuse and is tiny; h is the stream that misses)
//   - keep: ushort col, BK=64 GEMM, prep fusion, round-8 msgpass structure
//   - msgpass equilibrium (6 attacks neutral/negative): 820 MB/pass gather
//     at ~7.8 TB/s effective, 46% HBM + 56% L2-hit, occ 70%
// ---------------------------------------------------------------------------

#define NNODES 50000
#define DDIM 256
#define SCAN_B 256
#define SCAN_G ((NNODES + SCAN_B - 1) / SCAN_B)   // 196

typedef __attribute__((ext_vector_type(8))) short short8;
typedef __attribute__((ext_vector_type(4))) float float4_;
typedef __attribute__((ext_vector_type(2))) float float2_;

__device__ __forceinline__ float fast_tanh(float x) {
    float e = __expf(2.0f * x);
    return 1.0f - 2.0f / (e + 1.0f);
}

__device__ __forceinline__ float bf2f(unsigned short u) {
    return __uint_as_float(((unsigned)u) << 16);
}
__device__ __forceinline__ unsigned short f2bf(float f) {
    unsigned u = __float_as_uint(f);
    u = u + 0x7fffu + ((u >> 16) & 1u);   // round-to-nearest-even
    return (unsigned short)(u >> 16);
}

__device__ __forceinline__ unsigned f2key(float f) {
    unsigned b = __float_as_uint(f);
    return (b & 0x80000000u) ? ~b : (b | 0x80000000u);
}
__device__ __forceinline__ float key2f(unsigned k) {
    unsigned b = (k & 0x80000000u) ? (k & 0x7fffffffu) : ~k;
    return __uint_as_float(b);
}

// ---------------- CSR build ----------------
__global__ void hist_kernel(const int* __restrict__ ei, int* __restrict__ deg,
                            int* __restrict__ rank, int E) {
    int e = blockIdx.x * blockDim.x + threadIdx.x;
    if (e < E) rank[e] = atomicAdd(&deg[ei[E + e]], 1);
}

__global__ void scan1_kernel(const int* __restrict__ deg, int* __restrict__ bsum, int N) {
    __shared__ int s[SCAN_B];
    int t = threadIdx.x;
    int idx = blockIdx.x * SCAN_B + t;
    s[t] = (idx < N) ? deg[idx] : 0;
    __syncthreads();
    for (int off = SCAN_B / 2; off > 0; off >>= 1) {
        if (t < off) s[t] += s[t + off];
        __syncthreads();
    }
    if (t == 0) bsum[blockIdx.x] = s[0];
}

__global__ void scan2_kernel(const int* __restrict__ deg, const int* __restrict__ bsum,
                             int* __restrict__ rowptr, float* __restrict__ dis, int N) {
    __shared__ int s[SCAN_B];
    __shared__ int bs[SCAN_B];
    int t = threadIdx.x;
    int bid = blockIdx.x;
    int idx = bid * SCAN_B + t;
    int d = (idx < N) ? deg[idx] : 0;
    s[t] = d;
    bs[t] = (t < bid) ? bsum[t] : 0;      // SCAN_G (196) <= SCAN_B (256)
    __syncthreads();
    for (int off = 1; off < SCAN_B; off <<= 1) {
        int v = (t >= off) ? s[t - off] : 0;
        __syncthreads();
        s[t] += v;
        __syncthreads();
    }
    for (int off = SCAN_B / 2; off > 0; off >>= 1) {
        if (t < off) bs[t] += bs[t + off];
        __syncthreads();
    }
    if (idx < N) {
        rowptr[idx] = bs[0] + s[t] - d;   // exclusive
        dis[idx] = rsqrtf(1.0f + (float)d);
    }
}

__global__ void scatter_kernel(const int* __restrict__ ei, const int* __restrict__ rowptr,
                               const int* __restrict__ rank,
                               unsigned short* __restrict__ col, int E) {
    int e = blockIdx.x * blockDim.x + threadIdx.x;
    if (e < E) {
        int d = ei[E + e];
        col[rowptr[d] + rank[e]] = (unsigned short)ei[e];
    }
}

// ---------------- prep: cast x (pre-scaled by dis) + 4 weight transposes ----
#define CAST_BLOCKS ((NNODES * 128) / 256)     // 25000
__global__ void prep_kernel(const float* __restrict__ x, const float* __restrict__ dis,
                            unsigned short* __restrict__ xh,
                            const float* __restrict__ W0, const float* __restrict__ W1,
                            const float* __restrict__ W2, const float* __restrict__ W3,
                            unsigned short* __restrict__ wt0, unsigned short* __restrict__ wt1,
                            unsigned short* __restrict__ wt2, unsigned short* __restrict__ wt3) {
    int b = blockIdx.x;
    int t = threadIdx.x;
    if (b < CAST_BLOCKS) {
        int i = b * 256 + t;
        xh[i] = f2bf(x[i] * dis[i >> 7]);   // 128 feats per row
        return;
    }
    b -= CAST_BLOCKS;
    const float* W; unsigned short* Wt; int K; int k;
    if (b < 128)      { W = W0; Wt = wt0; K = 128; k = b; }
    else if (b < 384) { W = W1; Wt = wt1; K = 256; k = b - 128; }
    else if (b < 640) { W = W2; Wt = wt2; K = 256; k = b - 384; }
    else              { W = W3; Wt = wt3; K = 256; k = b - 640; }
    Wt[t * K + k] = f2bf(W[k * 256 + t]);
}

// ---------------- message passing (round-8 form, frozen) ----------------
// in rows pre-scaled by dis[src]; out[n] = dis[n]*(sum in[src] + in[n]).
// Lane covers 8 feats (16B); P = 512/D edges per wave-issue; acc = 4x float2.
__device__ __forceinline__ void paddu(float2_* acc, uint4 u) {
    float2_ v0 = {__uint_as_float(u.x << 16), __uint_as_float(u.x & 0xffff0000u)};
    float2_ v1 = {__uint_as_float(u.y << 16), __uint_as_float(u.y & 0xffff0000u)};
    float2_ v2 = {__uint_as_float(u.z << 16), __uint_as_float(u.z & 0xffff0000u)};
    float2_ v3 = {__uint_as_float(u.w << 16), __uint_as_float(u.w & 0xffff0000u)};
    acc[0] += v0; acc[1] += v1; acc[2] += v2; acc[3] += v3;
}
__device__ __forceinline__ void paddw(float2_* acc, uint4 u, float w) {
    float2_ w2 = {w, w};
    float2_ v0 = {__uint_as_float(u.x << 16), __uint_as_float(u.x & 0xffff0000u)};
    float2_ v1 = {__uint_as_float(u.y << 16), __uint_as_float(u.y & 0xffff0000u)};
    float2_ v2 = {__uint_as_float(u.z << 16), __uint_as_float(u.z & 0xffff0000u)};
    float2_ v3 = {__uint_as_float(u.w << 16), __uint_as_float(u.w & 0xffff0000u)};
    acc[0] += v0 * w2; acc[1] += v1 * w2; acc[2] += v2 * w2; acc[3] += v3 * w2;
}

template <int D, bool FINALIZE>
__global__ void msgpass_bf16(const unsigned short* __restrict__ in,
                             unsigned short* __restrict__ out,
                             const int* __restrict__ rowptr, const int* __restrict__ deg,
                             const unsigned short* __restrict__ col,
                             const float* __restrict__ dis, const float* __restrict__ bias) {
    constexpr int L = D / 8;
    constexpr int P = 64 / L;
    int lane = threadIdx.x & 63;
    int wav  = threadIdx.x >> 6;
    int n = blockIdx.x * 8 + wav;   // block = 512 threads = 8 waves
    if (n >= NNODES) return;
    int part = lane / L;
    int sl   = lane % L;
    int start = rowptr[n];
    int cnt   = deg[n];
    float dn = dis[n];
    float2_ acc[4];
#pragma unroll
    for (int j = 0; j < 4; ++j) { float2_ z = {0.0f, 0.0f}; acc[j] = z; }

    int e = 0;
    for (; e + 4 * P <= cnt; e += 4 * P) {
        int c0 = col[start + e + part];
        int c1 = col[start + e + P + part];
        int c2 = col[start + e + 2 * P + part];
        int c3 = col[start + e + 3 * P + part];
        uint4 u0 = *((const uint4*)(in + (size_t)c0 * D) + sl);
        uint4 u1 = *((const uint4*)(in + (size_t)c1 * D) + sl);
        uint4 u2 = *((const uint4*)(in + (size_t)c2 * D) + sl);
        uint4 u3 = *((const uint4*)(in + (size_t)c3 * D) + sl);
        paddu(acc, u0);
        paddu(acc, u1);
        paddu(acc, u2);
        paddu(acc, u3);
    }
    for (; e + P <= cnt; e += P) {
        int c = col[start + e + part];
        uint4 u = *((const uint4*)(in + (size_t)c * D) + sl);
        paddu(acc, u);
    }
    int r = cnt - e;
    if (r > 0) {
        int c = (part < r) ? (int)col[start + e + part] : n;
        float w = (part < r) ? 1.0f : 0.0f;
        uint4 u = *((const uint4*)(in + (size_t)c * D) + sl);
        paddw(acc, u, w);
    }
    {   // self term: + in[n] (part 0 only)
        float w = (part == 0) ? 1.0f : 0.0f;
        uint4 u = *((const uint4*)(in + (size_t)n * D) + sl);
        paddw(acc, u, w);
    }
    // reduce across parts (butterfly)
#pragma unroll
    for (int j = 0; j < 4; ++j) {
#pragma unroll
        for (int h = 0; h < 2; ++h) {
            if (P == 4) acc[j][h] += __shfl(acc[j][h], lane ^ 16);
            acc[j][h] += __shfl(acc[j][h], lane ^ 32);
        }
    }
    if (part == 0) {
        float a[8] = {acc[0][0], acc[0][1], acc[1][0], acc[1][1],
                      acc[2][0], acc[2][1], acc[3][0], acc[3][1]};
        if (FINALIZE) {
#pragma unroll
            for (int j = 0; j < 8; ++j)
                a[j] = fast_tanh(fmaf(a[j], dn, bias[sl * 8 + j]));
        } else {
#pragma unroll
            for (int j = 0; j < 8; ++j)
                a[j] *= dn;
        }
        uint4 o;
        o.x = (unsigned)f2bf(a[0]) | ((unsigned)f2bf(a[1]) << 16);
        o.y = (unsigned)f2bf(a[2]) | ((unsigned)f2bf(a[3]) << 16);
        o.z = (unsigned)f2bf(a[4]) | ((unsigned)f2bf(a[5]) << 16);
        o.w = (unsigned)f2bf(a[6]) | ((unsigned)f2bf(a[7]) << 16);
        *((uint4*)(out + (size_t)n * D) + sl) = o;
    }
}

// ---------------- MFMA GEMM: C[N,256] = A[N,K] * W[K,256], BK=64 ----------
// TANH: C = tanh(AW + bias); else C = dis[row]*(AW) (pre-scaled for msgpass).
template <int K, bool TANH>
__launch_bounds__(256, 2)
__global__ void gemm_mfma(const short* __restrict__ A, const short* __restrict__ Bt,
                          const float* __restrict__ bias, const float* __restrict__ dis,
                          unsigned short* __restrict__ C, int N) {
    constexpr int PK = 72;   // 64 + 8 pad (16B-aligned segments)
    __shared__ __align__(16) short As[128 * PK];
    __shared__ __align__(16) short Bs[128 * PK];
    int t = threadIdx.x;
    int lane = t & 63;
    int w    = t >> 6;
    int wr = w & 1;
    int wc = w >> 1;
    int m0 = blockIdx.x * 128;
    int n0 = blockIdx.y * 128;

    int srow = t >> 2;           // 0..63
    int koff = (t & 3) * 8;      // 0,8,16,24
    int arow0 = m0 + srow;      if (arow0 > N - 1) arow0 = N - 1;
    int arow1 = m0 + 64 + srow; if (arow1 > N - 1) arow1 = N - 1;
    const short8* ap0 = (const short8*)(A + (size_t)arow0 * K + koff);
    const short8* ap1 = (const short8*)(A + (size_t)arow1 * K + koff);
    const short8* bp0 = (const short8*)(Bt + (size_t)(n0 + srow) * K + koff);
    const short8* bp1 = (const short8*)(Bt + (size_t)(n0 + 64 + srow) * K + koff);

    float4_ acc[4][4];
#pragma unroll
    for (int i = 0; i < 4; ++i)
#pragma unroll
        for (int j = 0; j < 4; ++j) {
            float4_ z = {0.0f, 0.0f, 0.0f, 0.0f};
            acc[i][j] = z;
        }

    constexpr int NKB = K / 64;       // 4 for K=256, 2 for K=128
    int g = lane >> 4;
    int r = lane & 15;

    short8 a00 = ap0[0], a01 = ap0[4];
    short8 a10 = ap1[0], a11 = ap1[4];
    short8 b00 = bp0[0], b01 = bp0[4];
    short8 b10 = bp1[0], b11 = bp1[4];

    for (int kb = 0; kb < NKB; ++kb) {
        __syncthreads();
        *(short8*)&As[srow * PK + koff]             = a00;
        *(short8*)&As[srow * PK + koff + 32]        = a01;
        *(short8*)&As[(64 + srow) * PK + koff]      = a10;
        *(short8*)&As[(64 + srow) * PK + koff + 32] = a11;
        *(short8*)&Bs[srow * PK + koff]             = b00;
        *(short8*)&Bs[srow * PK + koff + 32]        = b01;
        *(short8*)&Bs[(64 + srow) * PK + koff]      = b10;
        *(short8*)&Bs[(64 + srow) * PK + koff + 32] = b11;
        __syncthreads();
        if (kb + 1 < NKB) {
            int o = (kb + 1) * 8;
            a00 = ap0[o]; a01 = ap0[o + 4];
            a10 = ap1[o]; a11 = ap1[o + 4];
            b00 = bp0[o]; b01 = bp0[o + 4];
            b10 = bp1[o]; b11 = bp1[o + 4];
        }
#pragma unroll
        for (int s = 0; s < 2; ++s) {
            short8 af[4], bfr[4];
#pragma unroll
            for (int i = 0; i < 4; ++i)
                af[i] = *(const short8*)&As[(wr * 64 + i * 16 + r) * PK + s * 32 + g * 8];
#pragma unroll
            for (int j = 0; j < 4; ++j)
                bfr[j] = *(const short8*)&Bs[(wc * 64 + j * 16 + r) * PK + s * 32 + g * 8];
#pragma unroll
            for (int i = 0; i < 4; ++i)
#pragma unroll
                for (int j = 0; j < 4; ++j)
                    acc[i][j] = __builtin_amdgcn_mfma_f32_16x16x32_bf16(af[i], bfr[j],
                                                                        acc[i][j], 0, 0, 0);
        }
    }

#pragma unroll
    for (int i = 0; i < 4; ++i) {
        int rowb = m0 + wr * 64 + i * 16 + g * 4;
#pragma unroll
        for (int rr = 0; rr < 4; ++rr) {
            int row = rowb + rr;
            if (row < N) {
                float dsc = TANH ? 0.0f : dis[row];
#pragma unroll
                for (int j = 0; j < 4; ++j) {
                    int cb = n0 + wc * 64 + j * 16 + r;
                    float v = acc[i][j][rr];
                    if (TANH) v = fast_tanh(v + bias[cb]);
                    else      v = v * dsc;
                    C[(size_t)row * 256 + cb] = f2bf(v);
                }
            }
        }
    }
}

// ---------------- pooling (sorted batch index, run-flush), bf16 input -------
#define POOL_CHUNK 64
__global__ void pool_kernel(const unsigned short* __restrict__ act,
                            const int* __restrict__ batch,
                            float* __restrict__ gsum, unsigned* __restrict__ gmaxk,
                            int* __restrict__ gcnt, int N) {
    int t  = threadIdx.x;   // 256 = DDIM
    int n0 = blockIdx.x * POOL_CHUNK;
    if (n0 >= N) return;
    int n1 = n0 + POOL_CHUNK;
    if (n1 > N) n1 = N;
    int   cur = batch[n0];
    float sum = 0.0f, mx = -2.0f;
    int   run = 0;
    for (int n = n0; n < n1; ++n) {
        int g = batch[n];
        float v = bf2f(act[(size_t)n * DDIM + t]);
        if (g != cur) {
            atomicAdd(&gsum[cur * DDIM + t], sum);
            atomicMax(&gmaxk[cur * DDIM + t], f2key(mx));
            if (t == 0) atomicAdd(&gcnt[cur], run);
            cur = g; sum = 0.0f; mx = -2.0f; run = 0;
        }
        sum += v;
        mx = fmaxf(mx, v);
        run++;
    }
    atomicAdd(&gsum[cur * DDIM + t], sum);
    atomicMax(&gmaxk[cur * DDIM + t], f2key(mx));
    if (t == 0) atomicAdd(&gcnt[cur], run);
}

// ---------------- fused MLP (one WG per graph), fp32 ----------------
__global__ void mlp_kernel(const float* __restrict__ gsum, const unsigned* __restrict__ gmaxk,
                           const int* __restrict__ gcnt,
                           const float* __restrict__ fc1_w, const float* __restrict__ fc1_b,
                           const float* __restrict__ fc2_w, const float* __restrict__ fc2_b,
                           const float* __restrict__ out_w, const float* __restrict__ out_b,
                           float* __restrict__ out) {
    int g = blockIdx.x;
    int t = threadIdx.x;   // 256
    __shared__ float gv[512];
    __shared__ float t1[512];
    __shared__ float t2[256];
    float cnt = fmaxf((float)gcnt[g], 1.0f);
    gv[t]       = key2f(gmaxk[g * DDIM + t]);
    gv[256 + t] = gsum[g * DDIM + t] / cnt;
    __syncthreads();
    float a0 = fc1_b[t], a1 = fc1_b[t + 256];
    for (int k = 0; k < 512; ++k) {
        float gk = gv[k];
        a0 = fmaf(gk, fc1_w[k * 512 + t], a0);
        a1 = fmaf(gk, fc1_w[k * 512 + t + 256], a1);
    }
    t1[t]       = fmaxf(a0, 0.0f);
    t1[t + 256] = fmaxf(a1, 0.0f);
    __syncthreads();
    float b0 = fc2_b[t];
    for (int k = 0; k < 512; ++k)
        b0 = fmaf(t1[k], fc2_w[k * 256 + t], b0);
    t2[t] = fmaxf(b0, 0.0f);
    __syncthreads();
    if (t < 10) {
        float o = out_b[t];
        for (int k = 0; k < 256; ++k)
            o = fmaf(t2[k], out_w[k * 10 + t], o);
        out[g * 10 + t] = o;
    }
}

// ---------------------------------------------------------------------------
extern "C" void kernel_launch(void* const* d_in, const int* in_sizes, int n_in,
                              void* d_out, int out_size, void* d_ws, size_t ws_size,
                              hipStream_t stream) {
    const float* x      = (const float*)d_in[0];
    const int*   ei     = (const int*)d_in[1];
    const int*   batch  = (const int*)d_in[2];
    const float* W0     = (const float*)d_in[3];
    const float* b0     = (const float*)d_in[4];
    const float* W1     = (const float*)d_in[5];
    const float* b1     = (const float*)d_in[6];
    const float* W2     = (const float*)d_in[7];
    const float* b2     = (const float*)d_in[8];
    const float* W3     = (const float*)d_in[9];
    const float* b3     = (const float*)d_in[10];
    const float* fc1_w  = (const float*)d_in[11];
    const float* fc1_b  = (const float*)d_in[12];
    const float* fc2_w  = (const float*)d_in[13];
    const float* fc2_b  = (const float*)d_in[14];
    const float* out_w  = (const float*)d_in[15];
    const float* out_b  = (const float*)d_in[16];
    float* out = (float*)d_out;

    const int N = in_sizes[2];          // 50000
    const int E = in_sizes[1] / 2;      // 1600000

    // workspace layout (bytes)
    char* ws = (char*)d_ws;
    const size_t off_deg    = 0;          // 200000
    const size_t off_gsum   = 200192;     // 65536
    const size_t off_gmaxk  = 265728;     // 65536
    const size_t off_gcnt   = 331264;     // 512
    const size_t ZERO_BYTES = 331776;
    const size_t off_dis    = 331776;     // 200000
    const size_t off_rowptr = 531968;     // 200000
    const size_t off_bsum   = 732160;     // 1024
    const size_t off_col    = 932352;     // E*2 = 3200000 (ushort)
    const size_t off_xh     = 7332352;    // 12800000
    const size_t off_wt0    = 20132352;   // 65536
    const size_t off_wt1    = 20197888;   // 131072
    const size_t off_wt2    = 20328960;   // 131072
    const size_t off_wt3    = 20460032;   // 131072
    const size_t off_bufA   = 20591104;   // 25600000
    const size_t off_bufB   = 46191104;   // 25600000

    int*            deg    = (int*)(ws + off_deg);
    float*          gsum   = (float*)(ws + off_gsum);
    unsigned*       gmaxk  = (unsigned*)(ws + off_gmaxk);
    int*            gcnt   = (int*)(ws + off_gcnt);
    float*          dis    = (float*)(ws + off_dis);
    int*            rowptr = (int*)(ws + off_rowptr);
    int*            bsum   = (int*)(ws + off_bsum);
    unsigned short* col    = (unsigned short*)(ws + off_col);
    unsigned short* xh     = (unsigned short*)(ws + off_xh);
    short*          wt0    = (short*)(ws + off_wt0);
    short*          wt1    = (short*)(ws + off_wt1);
    short*          wt2    = (short*)(ws + off_wt2);
    short*          wt3    = (short*)(ws + off_wt3);
    unsigned short* bufA   = (unsigned short*)(ws + off_bufA);
    unsigned short* bufB   = (unsigned short*)(ws + off_bufB);
    int*            rank   = (int*)(ws + off_bufA);   // overlay: dead before 1st GEMM

    hipMemsetAsync(ws, 0, ZERO_BYTES, stream);

    // CSR build
    hist_kernel<<<(E + 255) / 256, 256, 0, stream>>>(ei, deg, rank, E);
    scan1_kernel<<<SCAN_G, SCAN_B, 0, stream>>>(deg, bsum, N);
    scan2_kernel<<<SCAN_G, SCAN_B, 0, stream>>>(deg, bsum, rowptr, dis, N);
    scatter_kernel<<<(E + 255) / 256, 256, 0, stream>>>(ei, rowptr, rank, col, E);

    // prep: x cast (pre-scaled by dis) + all 4 weight transposes, one launch
    prep_kernel<<<CAST_BLOCKS + 896, 256, 0, stream>>>(
        x, dis, xh, W0, W1, W2, W3,
        (unsigned short*)wt0, (unsigned short*)wt1,
        (unsigned short*)wt2, (unsigned short*)wt3);

    // layer 0: agg0 = dis*(sum x'_src + x'_n) = A_hat x, then tanh(agg0 W0 + b0)
    msgpass_bf16<128, false><<<(N + 7) / 8, 512, 0, stream>>>(
        xh, bufB, rowptr, deg, col, dis, nullptr);
    gemm_mfma<128, true><<<dim3((N + 127) / 128, 2), 256, 0, stream>>>(
        (const short*)bufB, wt0, b0, dis, bufA, N);

    // layers 1..3: hW' = dis*(h W) (GEMM epilogue); h = tanh(dis*(sum hW'_src
    // + hW'_n) + b) == tanh(A_hat (h W) + b)
    const short* wts[3] = {wt1, wt2, wt3};
    const float* bs_[3] = {b1, b2, b3};
    for (int l = 0; l < 3; ++l) {
        gemm_mfma<256, false><<<dim3((N + 127) / 128, 2), 256, 0, stream>>>(
            (const short*)bufA, wts[l], nullptr, dis, bufB, N);
        msgpass_bf16<256, true><<<(N + 7) / 8, 512, 0, stream>>>(
            bufB, bufA, rowptr, deg, col, dis, bs_[l]);
    }

    // pooling + MLP (fp32)
    pool_kernel<<<(N + POOL_CHUNK - 1) / POOL_CHUNK, 256, 0, stream>>>(
        bufA, batch, gsum, gmaxk, gcnt, N);
    mlp_kernel<<<64, 256, 0, stream>>>(gsum, gmaxk, gcnt, fc1_w, fc1_b, fc2_w, fc2_b,
                                       out_w, out_b, out);
}